// Round 1
// baseline (108.811 us; speedup 1.0000x reference)
//
#include <hip/hip_runtime.h>
#include <math.h>

// Lee oscillator, element-wise, N-1 = 49 iterations.
// a = (0.6, 0.6, -0.5, 0.5, -0.6, -0.6, -0.5, 0.5), K = 50
//   u' = tanh(0.6u - 0.6v - 0.5z + 0.5x)
//   v' = tanh(-0.5z + 0.6u + 0.6v + 0.5x)    [a6*z - a4*u - a5*v + a7*x]
//   z' = (v' - u')*exp(-50 x^2) + tanh(x)
// Shared subexpression: s = 0.6u - 0.5z + 0.5x; argU = s - 0.6v; argV = s + 0.6v.

#define NITER 49

#if __has_builtin(__builtin_amdgcn_exp2f)
#define EXP2F(v) __builtin_amdgcn_exp2f(v)
#else
#define EXP2F(v) __expf((v) * 0.6931471805599453f)
#endif

// tanh(y) = 1 - 2/(exp(2y)+1), exp via v_exp_f32 (exp2), rcp via v_rcp_f32
// + one Newton step to reach ~1 ulp (recurrence is error-amplifying; keep
// per-step error at fp32 rounding scale).
__device__ __forceinline__ float fast_tanh(float y) {
    const float TWO_LOG2E = 2.885390081777927f;  // 2*log2(e)
    float e = EXP2F(y * TWO_LOG2E);              // exp(2y)
    float d = e + 1.0f;
    float r = __builtin_amdgcn_rcpf(d);
    // Newton refine: r = r*(2 - d*r)
    r = r * __builtin_fmaf(-d, r, 2.0f);
    return __builtin_fmaf(-2.0f, r, 1.0f);
}

__global__ __launch_bounds__(256) void lee_kernel(const float* __restrict__ x,
                                                  float* __restrict__ out,
                                                  int n4) {
    int i = blockIdx.x * blockDim.x + threadIdx.x;
    if (i >= n4) return;

    float4 xv = reinterpret_cast<const float4*>(x)[i];
    float xs[4] = {xv.x, xv.y, xv.z, xv.w};

    float u[4], v[4], z[4], decay[4], w[4], px[4];
    const float NK_LOG2E = -72.13475204444817f;  // -50*log2(e)

#pragma unroll
    for (int j = 0; j < 4; ++j) {
        float xx = xs[j];
        px[j] = 0.5f * xx;
        decay[j] = EXP2F(NK_LOG2E * xx * xx);    // exp(-50 x^2)
        w[j] = fast_tanh(xx);
        u[j] = 0.2f;
        v[j] = 0.0f;
        z[j] = 0.2f;
    }

    for (int it = 0; it < NITER; ++it) {
#pragma unroll
        for (int j = 0; j < 4; ++j) {
            float c = __builtin_fmaf(-0.5f, z[j], px[j]);   // -0.5z + 0.5x
            float s = __builtin_fmaf(0.6f, u[j], c);        // 0.6u - 0.5z + 0.5x
            float au = __builtin_fmaf(-0.6f, v[j], s);
            float av = __builtin_fmaf(0.6f, v[j], s);
            float un = fast_tanh(au);
            float vn = fast_tanh(av);
            z[j] = __builtin_fmaf(vn - un, decay[j], w[j]);
            u[j] = un;
            v[j] = vn;
        }
    }

    float4 ov;
    ov.x = z[0]; ov.y = z[1]; ov.z = z[2]; ov.w = z[3];
    reinterpret_cast<float4*>(out)[i] = ov;
}

extern "C" void kernel_launch(void* const* d_in, const int* in_sizes, int n_in,
                              void* d_out, int out_size, void* d_ws, size_t ws_size,
                              hipStream_t stream) {
    const float* x = (const float*)d_in[0];
    float* out = (float*)d_out;
    int n = in_sizes[0];        // 4*1024*512 = 2097152, divisible by 4
    int n4 = n / 4;
    int block = 256;
    int grid = (n4 + block - 1) / block;
    lee_kernel<<<grid, block, 0, stream>>>(x, out, n4);
}

// Round 2
// 101.726 us; speedup vs baseline: 1.0697x; 1.0697x over previous
//
#include <hip/hip_runtime.h>
#include <math.h>

// Lee oscillator, element-wise, N-1 = 49 iterations.
// a=(0.6,0.6,-0.5,0.5,-0.6,-0.6,-0.5,0.5), K=50
//   u' = tanh(0.6u - 0.6v - 0.5z + 0.5x)
//   v' = tanh(0.6u + 0.6v - 0.5z + 0.5x)
//   z' = (v' - u')*exp(-50 x^2) + tanh(x)
//
// Reformulated in r-space: for y with e = exp(2y), r = 1/(e+1):
//   tanh(y) = 1 - 2r.  So u = 1-2ru, v = 1-2rv, and
//   v' - u' = 2(ru - rv)  ->  z' = fma(ru - rv, 2*decay, w).
// Tanh-arg scale 2*log2(e) folded into all coefficients so exp is a raw
// v_exp_f32.  Per iteration per element: 10 VALU + 2 v_exp + 2 v_rcp.
// No Newton on rcp: HW rcp ~1 ulp; exp2 rounding dominates per-step error.

#define NITER 49

__global__ __launch_bounds__(256, 8) void lee_kernel(const float* __restrict__ x,
                                                     float* __restrict__ out,
                                                     int n4) {
    int i = blockIdx.x * blockDim.x + threadIdx.x;
    if (i >= n4) return;

    const float T   = 2.885390081777927f;     // 2*log2(e)
    const float C05 = 0.5f * T;               // 0.5 * 2log2e
    const float C06 = 0.6f * T;               // 0.6 * 2log2e
    const float NK  = -72.13475204444817f;    // -50*log2(e)

    float4 xv = reinterpret_cast<const float4*>(x)[i];
    float xs[4] = {xv.x, xv.y, xv.z, xv.w};

    float pxT[4], d2[4], w[4], u[4], v[4], z[4];

#pragma unroll
    for (int j = 0; j < 4; ++j) {
        float xx = xs[j];
        pxT[j] = C05 * xx;                                   // 0.5*T*x
        d2[j]  = 2.0f * __builtin_amdgcn_exp2f(NK * xx * xx); // 2*exp(-50 x^2)
        // w = tanh(x), computed once; keep a Newton step here (cheap, outside loop)
        float e = __builtin_amdgcn_exp2f(T * xx);
        float dd = e + 1.0f;
        float r = __builtin_amdgcn_rcpf(dd);
        r = r * __builtin_fmaf(-dd, r, 2.0f);
        w[j] = __builtin_fmaf(-2.0f, r, 1.0f);
        u[j] = 0.2f;
        v[j] = 0.0f;
        z[j] = 0.2f;
    }

    for (int it = 0; it < NITER; ++it) {
#pragma unroll
        for (int j = 0; j < 4; ++j) {
            float cT  = __builtin_fmaf(-C05, z[j], pxT[j]);  // T*(-0.5z + 0.5x)
            float sT  = __builtin_fmaf(C06, u[j], cT);       // +T*0.6u
            float auT = __builtin_fmaf(-C06, v[j], sT);      // 2log2e * arg_u
            float avT = __builtin_fmaf(C06, v[j], sT);       // 2log2e * arg_v
            float eu  = __builtin_amdgcn_exp2f(auT);         // exp(2*arg_u)
            float ev  = __builtin_amdgcn_exp2f(avT);
            float ru  = __builtin_amdgcn_rcpf(eu + 1.0f);
            float rv  = __builtin_amdgcn_rcpf(ev + 1.0f);
            u[j] = __builtin_fmaf(-2.0f, ru, 1.0f);          // tanh(arg_u)
            v[j] = __builtin_fmaf(-2.0f, rv, 1.0f);
            z[j] = __builtin_fmaf(ru - rv, d2[j], w[j]);     // (v'-u')*decay + w
        }
    }

    float4 ov;
    ov.x = z[0]; ov.y = z[1]; ov.z = z[2]; ov.w = z[3];
    reinterpret_cast<float4*>(out)[i] = ov;
}

extern "C" void kernel_launch(void* const* d_in, const int* in_sizes, int n_in,
                              void* d_out, int out_size, void* d_ws, size_t ws_size,
                              hipStream_t stream) {
    const float* x = (const float*)d_in[0];
    float* out = (float*)d_out;
    int n = in_sizes[0];        // 4*1024*512 = 2097152, divisible by 4
    int n4 = n / 4;
    int block = 256;
    int grid = (n4 + block - 1) / block;
    lee_kernel<<<grid, block, 0, stream>>>(x, out, n4);
}

// Round 3
// 92.937 us; speedup vs baseline: 1.1708x; 1.0946x over previous
//
#include <hip/hip_runtime.h>

// Lee oscillator, element-wise, 49 iterations.
//   u' = tanh(0.6u - 0.6v - 0.5z + 0.5x)
//   v' = tanh(0.6u + 0.6v - 0.5z + 0.5x)
//   z' = (v'-u')*exp(-50 x^2) + tanh(x)
//
// r-space form: e=exp(2y), tanh(y) = 1 - 2/(e+1).
// Merged reciprocal: A=eu+1, B=ev+1, rp=rcp(A*B) -> ru=B*rp, rv=A*rp
//   u' = fma(B, -2rp, 1); v' = fma(A, -2rp, 1); ru-rv = (B-A)*rp.
// All polynomial-free VALU written on float2 ext-vectors so LLVM selects
// packed fp32 (v_pk_fma_f32 etc., gfx90a+/gfx950): halves VALU issue cycles.
// Per element-iter: 6.5 packed-VALU issues + 2 v_exp + 1 v_rcp.

typedef float v2f __attribute__((ext_vector_type(2)));

#define NITER 49

__device__ __forceinline__ float exp2f_hw(float a) { return __builtin_amdgcn_exp2f(a); }
__device__ __forceinline__ float rcpf_hw(float a) { return __builtin_amdgcn_rcpf(a); }

__global__ __launch_bounds__(256, 8) void lee_kernel(const float* __restrict__ x,
                                                     float* __restrict__ out,
                                                     int n4) {
    int i = blockIdx.x * blockDim.x + threadIdx.x;
    if (i >= n4) return;

    const float T   = 2.885390081777927f;     // 2*log2(e)
    const float C05 = 0.5f * T;
    const float C06 = 0.6f * T;
    const float NK  = -72.13475204444817f;    // -50*log2(e)

    const v2f vC05n = {-C05, -C05};
    const v2f vC06  = { C06,  C06};
    const v2f vC06n = {-C06, -C06};
    const v2f vone  = { 1.0f, 1.0f};
    const v2f vn2   = {-2.0f, -2.0f};

    float4 xv = reinterpret_cast<const float4*>(x)[i];
    v2f X[2];
    X[0] = (v2f){xv.x, xv.y};
    X[1] = (v2f){xv.z, xv.w};

    v2f pxT[2], d2[2], w[2], u[2], v[2], z[2];

#pragma unroll
    for (int c = 0; c < 2; ++c) {
        v2f xx = X[c];
        pxT[c] = (v2f){C05, C05} * xx;
        v2f ax = (v2f){NK, NK} * xx * xx;                 // -50*log2e*x^2
        d2[c] = (v2f){2.0f * exp2f_hw(ax.x), 2.0f * exp2f_hw(ax.y)};
        // w = tanh(x), once, with Newton-refined rcp (accuracy anchor)
        v2f tx = (v2f){T, T} * xx;
        v2f e  = (v2f){exp2f_hw(tx.x), exp2f_hw(tx.y)};
        v2f dd = e + vone;
        v2f r  = (v2f){rcpf_hw(dd.x), rcpf_hw(dd.y)};
        r = r * __builtin_elementwise_fma(-dd, r, (v2f){2.0f, 2.0f});
        w[c] = __builtin_elementwise_fma(vn2, r, vone);
        u[c] = (v2f){0.2f, 0.2f};
        v[c] = (v2f){0.0f, 0.0f};
        z[c] = (v2f){0.2f, 0.2f};
    }

    for (int it = 0; it < NITER; ++it) {
#pragma unroll
        for (int c = 0; c < 2; ++c) {
            v2f cT  = __builtin_elementwise_fma(vC05n, z[c], pxT[c]);  // T*(0.5x-0.5z)
            v2f sT  = __builtin_elementwise_fma(vC06,  u[c], cT);      // +T*0.6u
            v2f auT = __builtin_elementwise_fma(vC06n, v[c], sT);
            v2f avT = __builtin_elementwise_fma(vC06,  v[c], sT);
            v2f EU = (v2f){exp2f_hw(auT.x), exp2f_hw(auT.y)};          // exp(2*arg_u)
            v2f EV = (v2f){exp2f_hw(avT.x), exp2f_hw(avT.y)};
            v2f A = EU + vone;
            v2f B = EV + vone;
            v2f P = A * B;
            v2f RP = (v2f){rcpf_hw(P.x), rcpf_hw(P.y)};                // 1/(A*B)
            v2f R2 = vn2 * RP;                                         // -2/(A*B)
            u[c] = __builtin_elementwise_fma(B, R2, vone);             // 1-2ru
            v[c] = __builtin_elementwise_fma(A, R2, vone);             // 1-2rv
            v2f Q = B - A;                                             // ev-eu
            z[c] = __builtin_elementwise_fma(Q * RP, d2[c], w[c]);     // (ru-rv)*2decay+w
        }
    }

    float4 ov;
    ov.x = z[0].x; ov.y = z[0].y; ov.z = z[1].x; ov.w = z[1].y;
    reinterpret_cast<float4*>(out)[i] = ov;
}

extern "C" void kernel_launch(void* const* d_in, const int* in_sizes, int n_in,
                              void* d_out, int out_size, void* d_ws, size_t ws_size,
                              hipStream_t stream) {
    const float* x = (const float*)d_in[0];
    float* out = (float*)d_out;
    int n = in_sizes[0];        // 2097152, divisible by 4
    int n4 = n / 4;
    int block = 256;
    int grid = (n4 + block - 1) / block;
    lee_kernel<<<grid, block, 0, stream>>>(x, out, n4);
}